// Round 6
// baseline (968.554 us; speedup 1.0000x reference)
//
#include <hip/hip_runtime.h>
#include <math.h>

#define NHEADS 4
#define HDIM 32
#define F 128   // Fin == H*C == 128 for both layers

typedef __attribute__((ext_vector_type(8))) short bf16x8;
typedef __attribute__((ext_vector_type(4))) float f32x4;

__device__ __forceinline__ float lrelu(float v) { return v > 0.f ? v : 0.2f * v; }

__device__ __forceinline__ unsigned short cvt_bf16(float f) {
    unsigned u = __float_as_uint(f);
    u += 0x7fffu + ((u >> 16) & 1u);     // round-to-nearest-even
    return (unsigned short)(u >> 16);
}

// ---------------- W pre-pack into MFMA B-fragment order (bf16) ----------------
// B fragment for v_mfma_f32_16x16x32_bf16: col = lane&15, k = (lane>>4)*8 + j
// Packed: Wb[frag*512 + lane*8 + j], frag = kk*9 + ct, ct = 0..8.
// ct==8 is the fused-alpha fragment: cols 0-3 = (W @ a_src)[k][head],
// cols 4-7 = (W @ a_dst)[k][head-4], cols 8-15 = 0.
__global__ void k_packW(const float* __restrict__ W, const float* __restrict__ a_src,
                        const float* __restrict__ a_dst, short* __restrict__ Wb) {
    int idx = blockIdx.x * 256 + threadIdx.x;
    if (idx >= 36 * 512) return;
    int j    = idx & 7;
    int lane = (idx >> 3) & 63;
    int frag = idx >> 9;
    int kk = frag / 9, ct = frag % 9;
    int k = kk * 32 + (lane >> 4) * 8 + j;
    int col = lane & 15;
    float val;
    if (ct < 8) {
        val = W[k * F + ct * 16 + col];
    } else if (col < 8) {
        int head = col & 3;
        const float* av = (col < 4) ? a_src : a_dst;
        float sum = 0.f;
        #pragma unroll 8
        for (int c = 0; c < HDIM; ++c)
            sum += W[k * F + head * HDIM + c] * av[head * HDIM + c];
        val = sum;
    } else {
        val = 0.f;
    }
    Wb[idx] = (short)cvt_bf16(val);
}

// ---------------- MFMA GEMM: h = x @ W, fused alpha, bf16 h out ---------------
template<bool ABF16>
__global__ __launch_bounds__(256) void k_gemm_mfma(
    const void* __restrict__ xv, const short* __restrict__ Wb,
    unsigned short* __restrict__ hbf, float* __restrict__ as_out,
    float* __restrict__ ad_out, int N)
{
    const int wid  = threadIdx.x >> 6;
    const int lane = threadIdx.x & 63;
    const int rowbase = blockIdx.x * 64 + wid * 16;
    const int row  = rowbase + (lane & 15);
    const int rowc = min(row, N - 1);
    const int col = lane & 15;

    f32x4 acc[9] = {};
    #pragma unroll
    for (int kk = 0; kk < 4; ++kk) {
        bf16x8 a;
        if constexpr (ABF16) {
            const unsigned short* xr =
                (const unsigned short*)xv + (size_t)rowc * F + (lane >> 4) * 8;
            a = *(const bf16x8*)(xr + kk * 32);
        } else {
            const float* xr = (const float*)xv + (size_t)rowc * F + (lane >> 4) * 8;
            float4 xa = *(const float4*)(xr + kk * 32);
            float4 xb = *(const float4*)(xr + kk * 32 + 4);
            a[0] = cvt_bf16(xa.x); a[1] = cvt_bf16(xa.y);
            a[2] = cvt_bf16(xa.z); a[3] = cvt_bf16(xa.w);
            a[4] = cvt_bf16(xb.x); a[5] = cvt_bf16(xb.y);
            a[6] = cvt_bf16(xb.z); a[7] = cvt_bf16(xb.w);
        }
        const bf16x8* bp = (const bf16x8*)(Wb + (size_t)(kk * 9) * 512 + lane * 8);
        #pragma unroll
        for (int ct = 0; ct < 9; ++ct) {
            bf16x8 b = bp[ct * 64];
            acc[ct] = __builtin_amdgcn_mfma_f32_16x16x32_bf16(a, b, acc[ct], 0, 0, 0);
        }
    }

    // C/D layout: col = lane&15, row = (lane>>4)*4 + reg
    const int r0 = rowbase + (lane >> 4) * 4;
    #pragma unroll
    for (int i = 0; i < 4; ++i) {
        int r = r0 + i;
        if (r < N) {
            #pragma unroll
            for (int ct = 0; ct < 8; ++ct)
                hbf[(size_t)r * F + ct * 16 + col] = cvt_bf16(acc[ct][i]);
            if (col < 4)       as_out[r * NHEADS + col]     = acc[8][i];
            else if (col < 8)  ad_out[r * NHEADS + col - 4] = acc[8][i];
        }
    }
}

// ---------------- CSR build: counting sort of edges by dst ----------------
__global__ void k_zero(int* __restrict__ p, int n) {
    int i = blockIdx.x * 256 + threadIdx.x;
    if (i < n) p[i] = 0;
}

__global__ void k_hist(const int* __restrict__ dst, int* __restrict__ deg, int E, int N) {
    int i = blockIdx.x * 256 + threadIdx.x;
    if (i >= E + N) return;
    int d = (i < E) ? dst[i] : (i - E);
    atomicAdd(&deg[d], 1);
}

__global__ void k_scan1(const int* __restrict__ deg, int* __restrict__ tmp,
                        int* __restrict__ bsum, int N) {
    __shared__ int sh[256];
    int t = threadIdx.x, i = blockIdx.x * 256 + t;
    sh[t] = (i < N) ? deg[i] : 0;
    __syncthreads();
    for (int off = 1; off < 256; off <<= 1) {
        int u = (t >= off) ? sh[t - off] : 0;
        __syncthreads();
        sh[t] += u;
        __syncthreads();
    }
    if (i < N) tmp[i] = sh[t];
    if (t == 255) bsum[blockIdx.x] = sh[255];
}

__global__ void k_scan2(const int* __restrict__ bsum, int* __restrict__ ebsum, int nblk) {
    __shared__ int sh[512];
    int t = threadIdx.x;
    int v = (t < nblk) ? bsum[t] : 0;
    sh[t] = v;
    __syncthreads();
    for (int off = 1; off < 512; off <<= 1) {
        int u = (t >= off) ? sh[t - off] : 0;
        __syncthreads();
        sh[t] += u;
        __syncthreads();
    }
    if (t < nblk) ebsum[t] = sh[t] - v;
}

__global__ void k_scan3(const int* __restrict__ tmp, const int* __restrict__ ebsum,
                        const int* __restrict__ deg, int* __restrict__ rowptr,
                        int* __restrict__ cursor, int N) {
    int i = blockIdx.x * 256 + threadIdx.x;
    if (i >= N) return;
    int incl = tmp[i] + ebsum[i >> 8];
    int excl = incl - deg[i];
    rowptr[i] = excl;
    cursor[i] = excl;
    if (i == N - 1) rowptr[N] = incl;
}

__global__ void k_scatter(const int* __restrict__ src, const int* __restrict__ dst,
                          int* __restrict__ cursor, int* __restrict__ ssrc, int E, int N) {
    int i = blockIdx.x * 256 + threadIdx.x;
    if (i >= E + N) return;
    int s, d;
    if (i < E) { s = src[i]; d = dst[i]; } else { s = d = i - E; }
    int pos = atomicAdd(&cursor[d], 1);
    ssrc[pos] = s;
}

// ---------------- degree sort (counting sort, 256 buckets) ----------------
__global__ void k_hist_deg(const int* __restrict__ deg, int* __restrict__ dhist, int N) {
    int i = blockIdx.x * 256 + threadIdx.x;
    if (i < N) atomicAdd(&dhist[min(deg[i], 255)], 1);
}

__global__ void k_scan_deg(const int* __restrict__ dhist, int* __restrict__ dcur) {
    __shared__ int sh[256];
    int t = threadIdx.x;
    int v = dhist[t];
    sh[t] = v;
    __syncthreads();
    for (int off = 1; off < 256; off <<= 1) {
        int u = (t >= off) ? sh[t - off] : 0;
        __syncthreads();
        sh[t] += u;
        __syncthreads();
    }
    dcur[t] = sh[t] - v;   // exclusive
}

__global__ void k_scatter_deg(const int* __restrict__ deg, int* __restrict__ dcur,
                              int* __restrict__ order, int N) {
    int i = blockIdx.x * 256 + threadIdx.x;
    if (i >= N) return;
    int pos = atomicAdd(&dcur[min(deg[i], 255)], 1);
    order[pos] = i;
}

// ---------------- single-pass softmax + weighted aggregation ----------------
// 16 lanes per node (degree-sorted order), 4 nodes per wave. Each lane owns 8
// channels of one head; the per-head denominator is lane-local (no reductions,
// no LDS). ssrc fetched 16-wide per chunk, broadcast via __shfl in-group.
template<bool OUTBF16>
__global__ __launch_bounds__(256) void k_aggregate(
    const int* __restrict__ rowptr, const int* __restrict__ ssrc,
    const int* __restrict__ order,
    const float* __restrict__ as, const float* __restrict__ ad,
    const unsigned short* __restrict__ hbf, const float* __restrict__ bias,
    void* __restrict__ outv, int N)
{
    int gi = (blockIdx.x * 256 + threadIdx.x) >> 4;   // global 16-lane group id
    if (gi >= N) return;
    const int node  = order[gi];
    const int l16   = threadIdx.x & 15;
    const int gbase = threadIdx.x & 48;               // group base lane in wave
    const int hb    = l16 >> 2;                       // head owning my channels
    const int c0    = l16 * 8;                        // first of my 8 channels
    const int start = rowptr[node], end = rowptr[node + 1];
    const float adB = ad[node * NHEADS + hb];

    float a0=0.f,a1=0.f,a2=0.f,a3=0.f,a4=0.f,a5=0.f,a6=0.f,a7=0.f;
    float dacc = 0.f;
    for (int base = start; base < end; base += 16) {
        int sv = ssrc[min(base + l16, end - 1)];
        int lim = min(16, end - base);
        for (int j = 0; j < lim; ++j) {
            int s = __shfl(sv, gbase | j);
            float ex = __expf(lrelu(as[s * NHEADS + hb] + adB));
            dacc += ex;
            uint4 hv = *(const uint4*)(hbf + (size_t)s * F + c0);
            a0 = fmaf(ex, __uint_as_float(hv.x << 16),         a0);
            a1 = fmaf(ex, __uint_as_float(hv.x & 0xffff0000u), a1);
            a2 = fmaf(ex, __uint_as_float(hv.y << 16),         a2);
            a3 = fmaf(ex, __uint_as_float(hv.y & 0xffff0000u), a3);
            a4 = fmaf(ex, __uint_as_float(hv.z << 16),         a4);
            a5 = fmaf(ex, __uint_as_float(hv.z & 0xffff0000u), a5);
            a6 = fmaf(ex, __uint_as_float(hv.w << 16),         a6);
            a7 = fmaf(ex, __uint_as_float(hv.w & 0xffff0000u), a7);
        }
    }
    float inv = 1.f / dacc;                // deg >= 1 (self-loop), all exp > 0
    float v[8] = {a0,a1,a2,a3,a4,a5,a6,a7};
    #pragma unroll
    for (int k = 0; k < 8; ++k) {
        float t = v[k] * inv + bias[c0 + k];
        v[k] = t > 0.f ? t : expm1f(t);
    }
    if (OUTBF16) {
        unsigned r0 = (unsigned)cvt_bf16(v[0]) | ((unsigned)cvt_bf16(v[1]) << 16);
        unsigned r1 = (unsigned)cvt_bf16(v[2]) | ((unsigned)cvt_bf16(v[3]) << 16);
        unsigned r2 = (unsigned)cvt_bf16(v[4]) | ((unsigned)cvt_bf16(v[5]) << 16);
        unsigned r3 = (unsigned)cvt_bf16(v[6]) | ((unsigned)cvt_bf16(v[7]) << 16);
        uint4 o = {r0, r1, r2, r3};
        *(uint4*)((unsigned short*)outv + (size_t)node * F + c0) = o;
    } else {
        float4 o0 = {v[0], v[1], v[2], v[3]};
        float4 o1 = {v[4], v[5], v[6], v[7]};
        float* op = (float*)outv + (size_t)node * F + c0;
        *(float4*)op       = o0;
        *(float4*)(op + 4) = o1;
    }
}

extern "C" void kernel_launch(void* const* d_in, const int* in_sizes, int n_in,
                              void* d_out, int out_size, void* d_ws, size_t ws_size,
                              hipStream_t stream)
{
    const float* x      = (const float*)d_in[0];
    const int*   eidx   = (const int*)d_in[1];
    const float* W1     = (const float*)d_in[2];
    const float* a_src1 = (const float*)d_in[3];
    const float* a_dst1 = (const float*)d_in[4];
    const float* b1     = (const float*)d_in[5];
    const float* W2     = (const float*)d_in[6];
    const float* a_src2 = (const float*)d_in[7];
    const float* a_dst2 = (const float*)d_in[8];
    const float* b2     = (const float*)d_in[9];

    const int N = in_sizes[0] / F;
    const int E = in_sizes[1] / 2;
    const int TOT = E + N;
    const int* src = eidx;
    const int* dst = eidx + E;

    // workspace layout
    unsigned short* hbf    = (unsigned short*)d_ws;        // N*F bf16
    unsigned short* out1bf = hbf + (size_t)N * F;          // N*F bf16
    float* as = (float*)(out1bf + (size_t)N * F);          // N*4
    float* ad = as + (size_t)N * NHEADS;                   // N*4
    int* deg    = (int*)(ad + (size_t)N * NHEADS);
    int* rowptr = deg + N;                                 // N+1
    int* cursor = rowptr + N + 1;                          // N
    int* bsum   = cursor + N;                              // <=512
    int* ebsum  = bsum + 512;                              // <=512
    int* tmp    = ebsum + 512;                             // N
    int* ssrc   = tmp + N;                                 // TOT
    int* order  = ssrc + TOT;                              // N
    int* dhist  = order + N;                               // 256
    int* dcur   = dhist + 256;                             // 256
    short* Wb1  = (short*)(((uintptr_t)(dcur + 256) + 15) & ~(uintptr_t)15); // 36*512
    short* Wb2  = Wb1 + 36 * 512;

    const int nblk = (N + 255) / 256;
    const int gemmBlocks = (N + 63) / 64;
    const int aggBlocks  = (N + 15) / 16;     // 16 nodes per 256-thread block

    // ---- W pre-pack + CSR build + degree sort (reused by both layers) ----
    k_packW<<<72, 256, 0, stream>>>(W1, a_src1, a_dst1, Wb1);
    k_packW<<<72, 256, 0, stream>>>(W2, a_src2, a_dst2, Wb2);
    k_zero<<<nblk, 256, 0, stream>>>(deg, N);
    k_zero<<<1, 256, 0, stream>>>(dhist, 256);
    k_hist<<<(TOT + 255) / 256, 256, 0, stream>>>(dst, deg, E, N);
    k_scan1<<<nblk, 256, 0, stream>>>(deg, tmp, bsum, N);
    k_scan2<<<1, 512, 0, stream>>>(bsum, ebsum, nblk);
    k_scan3<<<nblk, 256, 0, stream>>>(tmp, ebsum, deg, rowptr, cursor, N);
    k_scatter<<<(TOT + 255) / 256, 256, 0, stream>>>(src, dst, cursor, ssrc, E, N);
    k_hist_deg<<<nblk, 256, 0, stream>>>(deg, dhist, N);
    k_scan_deg<<<1, 256, 0, stream>>>(dhist, dcur);
    k_scatter_deg<<<nblk, 256, 0, stream>>>(deg, dcur, order, N);

    // ---- layer 1: x (f32) -> out1bf (bf16) ----
    k_gemm_mfma<false><<<gemmBlocks, 256, 0, stream>>>(x, Wb1, hbf, as, ad, N);
    k_aggregate<true><<<aggBlocks, 256, 0, stream>>>(rowptr, ssrc, order, as, ad, hbf, b1, out1bf, N);

    // ---- layer 2: out1bf (bf16) -> d_out (f32) ----
    k_gemm_mfma<true><<<gemmBlocks, 256, 0, stream>>>(out1bf, Wb2, hbf, as, ad, N);
    k_aggregate<false><<<aggBlocks, 256, 0, stream>>>(rowptr, ssrc, order, as, ad, hbf, b2, d_out, N);
}

// Round 7
// 353.391 us; speedup vs baseline: 2.7407x; 2.7407x over previous
//
#include <hip/hip_runtime.h>
#include <math.h>

#define NHEADS 4
#define HDIM 32
#define F 128   // Fin == H*C == 128 for both layers

typedef __attribute__((ext_vector_type(8))) short bf16x8;
typedef __attribute__((ext_vector_type(4))) float f32x4;

__device__ __forceinline__ float lrelu(float v) { return v > 0.f ? v : 0.2f * v; }

__device__ __forceinline__ unsigned short cvt_bf16(float f) {
    unsigned u = __float_as_uint(f);
    u += 0x7fffu + ((u >> 16) & 1u);     // round-to-nearest-even
    return (unsigned short)(u >> 16);
}

// ---------------- W pre-pack into MFMA B-fragment order (bf16) ----------------
// B fragment for v_mfma_f32_16x16x32_bf16: col = lane&15, k = (lane>>4)*8 + j
// Packed: Wb[frag*512 + lane*8 + j], frag = kk*9 + ct, ct = 0..8.
// ct==8 is the fused-alpha fragment: cols 0-3 = (W @ a_src)[k][head],
// cols 4-7 = (W @ a_dst)[k][head-4], cols 8-15 = 0.
__global__ void k_packW(const float* __restrict__ W, const float* __restrict__ a_src,
                        const float* __restrict__ a_dst, short* __restrict__ Wb) {
    int idx = blockIdx.x * 256 + threadIdx.x;
    if (idx >= 36 * 512) return;
    int j    = idx & 7;
    int lane = (idx >> 3) & 63;
    int frag = idx >> 9;
    int kk = frag / 9, ct = frag % 9;
    int k = kk * 32 + (lane >> 4) * 8 + j;
    int col = lane & 15;
    float val;
    if (ct < 8) {
        val = W[k * F + ct * 16 + col];
    } else if (col < 8) {
        int head = col & 3;
        const float* av = (col < 4) ? a_src : a_dst;
        float sum = 0.f;
        #pragma unroll 8
        for (int c = 0; c < HDIM; ++c)
            sum += W[k * F + head * HDIM + c] * av[head * HDIM + c];
        val = sum;
    } else {
        val = 0.f;
    }
    Wb[idx] = (short)cvt_bf16(val);
}

// ---------------- MFMA GEMM: h = x @ W, fused alpha, bf16 h out ---------------
template<bool ABF16>
__global__ __launch_bounds__(256) void k_gemm_mfma(
    const void* __restrict__ xv, const short* __restrict__ Wb,
    unsigned short* __restrict__ hbf, float* __restrict__ as_out,
    float* __restrict__ ad_out, int N)
{
    const int wid  = threadIdx.x >> 6;
    const int lane = threadIdx.x & 63;
    const int rowbase = blockIdx.x * 64 + wid * 16;
    const int row  = rowbase + (lane & 15);
    const int rowc = min(row, N - 1);
    const int col = lane & 15;

    f32x4 acc[9] = {};
    #pragma unroll
    for (int kk = 0; kk < 4; ++kk) {
        bf16x8 a;
        if constexpr (ABF16) {
            const unsigned short* xr =
                (const unsigned short*)xv + (size_t)rowc * F + (lane >> 4) * 8;
            a = *(const bf16x8*)(xr + kk * 32);
        } else {
            const float* xr = (const float*)xv + (size_t)rowc * F + (lane >> 4) * 8;
            float4 xa = *(const float4*)(xr + kk * 32);
            float4 xb = *(const float4*)(xr + kk * 32 + 4);
            a[0] = cvt_bf16(xa.x); a[1] = cvt_bf16(xa.y);
            a[2] = cvt_bf16(xa.z); a[3] = cvt_bf16(xa.w);
            a[4] = cvt_bf16(xb.x); a[5] = cvt_bf16(xb.y);
            a[6] = cvt_bf16(xb.z); a[7] = cvt_bf16(xb.w);
        }
        const bf16x8* bp = (const bf16x8*)(Wb + (size_t)(kk * 9) * 512 + lane * 8);
        #pragma unroll
        for (int ct = 0; ct < 9; ++ct) {
            bf16x8 b = bp[ct * 64];
            acc[ct] = __builtin_amdgcn_mfma_f32_16x16x32_bf16(a, b, acc[ct], 0, 0, 0);
        }
    }

    // C/D layout: col = lane&15, row = (lane>>4)*4 + reg
    const int r0 = rowbase + (lane >> 4) * 4;
    #pragma unroll
    for (int i = 0; i < 4; ++i) {
        int r = r0 + i;
        if (r < N) {
            #pragma unroll
            for (int ct = 0; ct < 8; ++ct)
                hbf[(size_t)r * F + ct * 16 + col] = cvt_bf16(acc[ct][i]);
            if (col < 4)       as_out[r * NHEADS + col]     = acc[8][i];
            else if (col < 8)  ad_out[r * NHEADS + col - 4] = acc[8][i];
        }
    }
}

// ---------------- CSR build: counting sort of edges by dst ----------------
__global__ void k_zero(int* __restrict__ p, int n) {
    int i = blockIdx.x * 256 + threadIdx.x;
    if (i < n) p[i] = 0;
}

__global__ void k_hist(const int* __restrict__ dst, int* __restrict__ deg, int E, int N) {
    int i = blockIdx.x * 256 + threadIdx.x;
    if (i >= E + N) return;
    int d = (i < E) ? dst[i] : (i - E);
    atomicAdd(&deg[d], 1);
}

__global__ void k_scan1(const int* __restrict__ deg, int* __restrict__ tmp,
                        int* __restrict__ bsum, int N) {
    __shared__ int sh[256];
    int t = threadIdx.x, i = blockIdx.x * 256 + t;
    sh[t] = (i < N) ? deg[i] : 0;
    __syncthreads();
    for (int off = 1; off < 256; off <<= 1) {
        int u = (t >= off) ? sh[t - off] : 0;
        __syncthreads();
        sh[t] += u;
        __syncthreads();
    }
    if (i < N) tmp[i] = sh[t];
    if (t == 255) bsum[blockIdx.x] = sh[255];
}

__global__ void k_scan2(const int* __restrict__ bsum, int* __restrict__ ebsum, int nblk) {
    __shared__ int sh[512];
    int t = threadIdx.x;
    int v = (t < nblk) ? bsum[t] : 0;
    sh[t] = v;
    __syncthreads();
    for (int off = 1; off < 512; off <<= 1) {
        int u = (t >= off) ? sh[t - off] : 0;
        __syncthreads();
        sh[t] += u;
        __syncthreads();
    }
    if (t < nblk) ebsum[t] = sh[t] - v;
}

__global__ void k_scan3(const int* __restrict__ tmp, const int* __restrict__ ebsum,
                        const int* __restrict__ deg, int* __restrict__ rowptr,
                        int* __restrict__ cursor, int N) {
    int i = blockIdx.x * 256 + threadIdx.x;
    if (i >= N) return;
    int incl = tmp[i] + ebsum[i >> 8];
    int excl = incl - deg[i];
    rowptr[i] = excl;
    cursor[i] = excl;
    if (i == N - 1) rowptr[N] = incl;
}

__global__ void k_scatter(const int* __restrict__ src, const int* __restrict__ dst,
                          int* __restrict__ cursor, int* __restrict__ ssrc, int E, int N) {
    int i = blockIdx.x * 256 + threadIdx.x;
    if (i >= E + N) return;
    int s, d;
    if (i < E) { s = src[i]; d = dst[i]; } else { s = d = i - E; }
    int pos = atomicAdd(&cursor[d], 1);
    ssrc[pos] = s;
}

// ------------- degree sort: block-local counting sort (no global atomics) ------
// S1: per-block (1024 nodes) LDS histogram -> bh[blk][256]
__global__ __launch_bounds__(256) void k_sort_hist(
    const int* __restrict__ deg, int* __restrict__ bh, int N)
{
    __shared__ int hist[256];
    int t = threadIdx.x;
    hist[t] = 0;
    __syncthreads();
    int base = blockIdx.x * 1024;
    #pragma unroll
    for (int g = 0; g < 4; ++g) {
        int i = base + g * 256 + t;
        if (i < N) atomicAdd(&hist[min(deg[i], 255)], 1);
    }
    __syncthreads();
    bh[blockIdx.x * 256 + t] = hist[t];
}

// S2: single block; thread t = bucket t. Per-bucket prefix over blocks (coalesced),
// then bucket-base exclusive scan, then add base back. bh becomes start offsets.
__global__ __launch_bounds__(256) void k_sort_off(int* __restrict__ bh, int nb)
{
    int t = threadIdx.x;
    int run = 0;
    for (int j = 0; j < nb; ++j) {
        int v = bh[j * 256 + t];
        bh[j * 256 + t] = run;
        run += v;
    }
    __shared__ int sh[256];
    int tot = run;
    sh[t] = tot;
    __syncthreads();
    for (int off = 1; off < 256; off <<= 1) {
        int u = (t >= off) ? sh[t - off] : 0;
        __syncthreads();
        sh[t] += u;
        __syncthreads();
    }
    int bucket_base = sh[t] - tot;   // exclusive
    for (int j = 0; j < nb; ++j)
        bh[j * 256 + t] += bucket_base;
}

// S3: per-block LDS cursors seeded from bh; LDS atomics for rank; write order.
__global__ __launch_bounds__(256) void k_sort_scatter(
    const int* __restrict__ deg, const int* __restrict__ bh,
    int* __restrict__ order, int N)
{
    __shared__ int cur[256];
    int t = threadIdx.x;
    cur[t] = bh[blockIdx.x * 256 + t];
    __syncthreads();
    int base = blockIdx.x * 1024;
    #pragma unroll
    for (int g = 0; g < 4; ++g) {
        int i = base + g * 256 + t;
        if (i < N) {
            int pos = atomicAdd(&cur[min(deg[i], 255)], 1);
            order[pos] = i;
        }
    }
}

// ---------------- single-pass softmax + weighted aggregation ----------------
// 16 lanes per node (degree-sorted order), 4 nodes per wave. Each lane owns 8
// channels of one head; per-head denominator is lane-local (no reductions, no
// LDS). ssrc fetched 16-wide per chunk, broadcast via __shfl in-group.
template<bool OUTBF16>
__global__ __launch_bounds__(256) void k_aggregate(
    const int* __restrict__ rowptr, const int* __restrict__ ssrc,
    const int* __restrict__ order,
    const float* __restrict__ as, const float* __restrict__ ad,
    const unsigned short* __restrict__ hbf, const float* __restrict__ bias,
    void* __restrict__ outv, int N)
{
    int gi = (blockIdx.x * 256 + threadIdx.x) >> 4;   // global 16-lane group id
    if (gi >= N) return;
    const int node  = order[gi];
    const int l16   = threadIdx.x & 15;
    const int gbase = threadIdx.x & 48;               // group base lane in wave
    const int hb    = l16 >> 2;                       // head owning my channels
    const int c0    = l16 * 8;                        // first of my 8 channels
    const int start = rowptr[node], end = rowptr[node + 1];
    const float adB = ad[node * NHEADS + hb];

    float a0=0.f,a1=0.f,a2=0.f,a3=0.f,a4=0.f,a5=0.f,a6=0.f,a7=0.f;
    float dacc = 0.f;
    for (int base = start; base < end; base += 16) {
        int sv = ssrc[min(base + l16, end - 1)];
        int lim = min(16, end - base);
        for (int j = 0; j < lim; ++j) {
            int s = __shfl(sv, gbase | j);
            float ex = __expf(lrelu(as[s * NHEADS + hb] + adB));
            dacc += ex;
            uint4 hv = *(const uint4*)(hbf + (size_t)s * F + c0);
            a0 = fmaf(ex, __uint_as_float(hv.x << 16),         a0);
            a1 = fmaf(ex, __uint_as_float(hv.x & 0xffff0000u), a1);
            a2 = fmaf(ex, __uint_as_float(hv.y << 16),         a2);
            a3 = fmaf(ex, __uint_as_float(hv.y & 0xffff0000u), a3);
            a4 = fmaf(ex, __uint_as_float(hv.z << 16),         a4);
            a5 = fmaf(ex, __uint_as_float(hv.z & 0xffff0000u), a5);
            a6 = fmaf(ex, __uint_as_float(hv.w << 16),         a6);
            a7 = fmaf(ex, __uint_as_float(hv.w & 0xffff0000u), a7);
        }
    }
    float inv = 1.f / dacc;                // deg >= 1 (self-loop), all exp > 0
    float v[8] = {a0,a1,a2,a3,a4,a5,a6,a7};
    #pragma unroll
    for (int k = 0; k < 8; ++k) {
        float t = v[k] * inv + bias[c0 + k];
        v[k] = t > 0.f ? t : expm1f(t);
    }
    if (OUTBF16) {
        unsigned r0 = (unsigned)cvt_bf16(v[0]) | ((unsigned)cvt_bf16(v[1]) << 16);
        unsigned r1 = (unsigned)cvt_bf16(v[2]) | ((unsigned)cvt_bf16(v[3]) << 16);
        unsigned r2 = (unsigned)cvt_bf16(v[4]) | ((unsigned)cvt_bf16(v[5]) << 16);
        unsigned r3 = (unsigned)cvt_bf16(v[6]) | ((unsigned)cvt_bf16(v[7]) << 16);
        uint4 o = {r0, r1, r2, r3};
        *(uint4*)((unsigned short*)outv + (size_t)node * F + c0) = o;
    } else {
        float4 o0 = {v[0], v[1], v[2], v[3]};
        float4 o1 = {v[4], v[5], v[6], v[7]};
        float* op = (float*)outv + (size_t)node * F + c0;
        *(float4*)op       = o0;
        *(float4*)(op + 4) = o1;
    }
}

extern "C" void kernel_launch(void* const* d_in, const int* in_sizes, int n_in,
                              void* d_out, int out_size, void* d_ws, size_t ws_size,
                              hipStream_t stream)
{
    const float* x      = (const float*)d_in[0];
    const int*   eidx   = (const int*)d_in[1];
    const float* W1     = (const float*)d_in[2];
    const float* a_src1 = (const float*)d_in[3];
    const float* a_dst1 = (const float*)d_in[4];
    const float* b1     = (const float*)d_in[5];
    const float* W2     = (const float*)d_in[6];
    const float* a_src2 = (const float*)d_in[7];
    const float* a_dst2 = (const float*)d_in[8];
    const float* b2     = (const float*)d_in[9];

    const int N = in_sizes[0] / F;
    const int E = in_sizes[1] / 2;
    const int TOT = E + N;
    const int* src = eidx;
    const int* dst = eidx + E;

    // workspace layout
    unsigned short* hbf    = (unsigned short*)d_ws;        // N*F bf16
    unsigned short* out1bf = hbf + (size_t)N * F;          // N*F bf16
    float* as = (float*)(out1bf + (size_t)N * F);          // N*4
    float* ad = as + (size_t)N * NHEADS;                   // N*4
    int* deg    = (int*)(ad + (size_t)N * NHEADS);
    int* rowptr = deg + N;                                 // N+1
    int* cursor = rowptr + N + 1;                          // N
    int* bsum   = cursor + N;                              // <=512
    int* ebsum  = bsum + 512;                              // <=512
    int* tmp    = ebsum + 512;                             // N
    int* ssrc   = tmp + N;                                 // TOT
    int* order  = ssrc + TOT;                              // N
    const int nb = (N + 1023) / 1024;                      // sort blocks
    int* bh     = order + N;                               // nb*256
    short* Wb1  = (short*)(((uintptr_t)(bh + (size_t)nb * 256) + 15) & ~(uintptr_t)15);
    short* Wb2  = Wb1 + 36 * 512;

    const int nblk = (N + 255) / 256;
    const int gemmBlocks = (N + 63) / 64;
    const int aggBlocks  = (N + 15) / 16;     // 16 nodes per 256-thread block

    // ---- W pre-pack + CSR build + degree sort (reused by both layers) ----
    k_packW<<<72, 256, 0, stream>>>(W1, a_src1, a_dst1, Wb1);
    k_packW<<<72, 256, 0, stream>>>(W2, a_src2, a_dst2, Wb2);
    k_zero<<<nblk, 256, 0, stream>>>(deg, N);
    k_hist<<<(TOT + 255) / 256, 256, 0, stream>>>(dst, deg, E, N);
    k_scan1<<<nblk, 256, 0, stream>>>(deg, tmp, bsum, N);
    k_scan2<<<1, 512, 0, stream>>>(bsum, ebsum, nblk);
    k_scan3<<<nblk, 256, 0, stream>>>(tmp, ebsum, deg, rowptr, cursor, N);
    k_scatter<<<(TOT + 255) / 256, 256, 0, stream>>>(src, dst, cursor, ssrc, E, N);
    k_sort_hist<<<nb, 256, 0, stream>>>(deg, bh, N);
    k_sort_off<<<1, 256, 0, stream>>>(bh, nb);
    k_sort_scatter<<<nb, 256, 0, stream>>>(deg, bh, order, N);

    // ---- layer 1: x (f32) -> out1bf (bf16) ----
    k_gemm_mfma<false><<<gemmBlocks, 256, 0, stream>>>(x, Wb1, hbf, as, ad, N);
    k_aggregate<true><<<aggBlocks, 256, 0, stream>>>(rowptr, ssrc, order, as, ad, hbf, b1, out1bf, N);

    // ---- layer 2: out1bf (bf16) -> d_out (f32) ----
    k_gemm_mfma<true><<<gemmBlocks, 256, 0, stream>>>(out1bf, Wb2, hbf, as, ad, N);
    k_aggregate<false><<<aggBlocks, 256, 0, stream>>>(rowptr, ssrc, order, as, ad, hbf, b2, d_out, N);
}

// Round 8
// 336.302 us; speedup vs baseline: 2.8800x; 1.0508x over previous
//
#include <hip/hip_runtime.h>
#include <math.h>

#define NHEADS 4
#define HDIM 32
#define F 128   // Fin == H*C == 128 for both layers

typedef __attribute__((ext_vector_type(8))) short bf16x8;
typedef __attribute__((ext_vector_type(4))) float f32x4;

__device__ __forceinline__ float lrelu(float v) { return v > 0.f ? v : 0.2f * v; }

__device__ __forceinline__ unsigned short cvt_bf16(float f) {
    unsigned u = __float_as_uint(f);
    u += 0x7fffu + ((u >> 16) & 1u);     // round-to-nearest-even
    return (unsigned short)(u >> 16);
}

// ---------------- W pre-pack into MFMA B-fragment order (bf16) ----------------
// B fragment for v_mfma_f32_16x16x32_bf16: col = lane&15, k = (lane>>4)*8 + j
// Packed: Wb[frag*512 + lane*8 + j], frag = kk*9 + ct, ct = 0..8.
// ct==8 is the fused-alpha fragment: cols 0-3 = (W @ a_src)[k][head],
// cols 4-7 = (W @ a_dst)[k][head-4], cols 8-15 = 0.
__global__ void k_packW(const float* __restrict__ W, const float* __restrict__ a_src,
                        const float* __restrict__ a_dst, short* __restrict__ Wb) {
    int idx = blockIdx.x * 256 + threadIdx.x;
    if (idx >= 36 * 512) return;
    int j    = idx & 7;
    int lane = (idx >> 3) & 63;
    int frag = idx >> 9;
    int kk = frag / 9, ct = frag % 9;
    int k = kk * 32 + (lane >> 4) * 8 + j;
    int col = lane & 15;
    float val;
    if (ct < 8) {
        val = W[k * F + ct * 16 + col];
    } else if (col < 8) {
        int head = col & 3;
        const float* av = (col < 4) ? a_src : a_dst;
        float sum = 0.f;
        #pragma unroll 8
        for (int c = 0; c < HDIM; ++c)
            sum += W[k * F + head * HDIM + c] * av[head * HDIM + c];
        val = sum;
    } else {
        val = 0.f;
    }
    Wb[idx] = (short)cvt_bf16(val);
}

// ---------------- MFMA GEMM: h = x @ W, fused alpha, bf16 h out ---------------
template<bool ABF16>
__global__ __launch_bounds__(256) void k_gemm_mfma(
    const void* __restrict__ xv, const short* __restrict__ Wb,
    unsigned short* __restrict__ hbf, float* __restrict__ as_out,
    float* __restrict__ ad_out, int N)
{
    const int wid  = threadIdx.x >> 6;
    const int lane = threadIdx.x & 63;
    const int rowbase = blockIdx.x * 64 + wid * 16;
    const int row  = rowbase + (lane & 15);
    const int rowc = min(row, N - 1);
    const int col = lane & 15;

    f32x4 acc[9] = {};
    #pragma unroll
    for (int kk = 0; kk < 4; ++kk) {
        bf16x8 a;
        if constexpr (ABF16) {
            const unsigned short* xr =
                (const unsigned short*)xv + (size_t)rowc * F + (lane >> 4) * 8;
            a = *(const bf16x8*)(xr + kk * 32);
        } else {
            const float* xr = (const float*)xv + (size_t)rowc * F + (lane >> 4) * 8;
            float4 xa = *(const float4*)(xr + kk * 32);
            float4 xb = *(const float4*)(xr + kk * 32 + 4);
            a[0] = cvt_bf16(xa.x); a[1] = cvt_bf16(xa.y);
            a[2] = cvt_bf16(xa.z); a[3] = cvt_bf16(xa.w);
            a[4] = cvt_bf16(xb.x); a[5] = cvt_bf16(xb.y);
            a[6] = cvt_bf16(xb.z); a[7] = cvt_bf16(xb.w);
        }
        const bf16x8* bp = (const bf16x8*)(Wb + (size_t)(kk * 9) * 512 + lane * 8);
        #pragma unroll
        for (int ct = 0; ct < 9; ++ct) {
            bf16x8 b = bp[ct * 64];
            acc[ct] = __builtin_amdgcn_mfma_f32_16x16x32_bf16(a, b, acc[ct], 0, 0, 0);
        }
    }

    // C/D layout: col = lane&15, row = (lane>>4)*4 + reg
    const int r0 = rowbase + (lane >> 4) * 4;
    #pragma unroll
    for (int i = 0; i < 4; ++i) {
        int r = r0 + i;
        if (r < N) {
            #pragma unroll
            for (int ct = 0; ct < 8; ++ct)
                hbf[(size_t)r * F + ct * 16 + col] = cvt_bf16(acc[ct][i]);
            if (col < 4)       as_out[r * NHEADS + col]     = acc[8][i];
            else if (col < 8)  ad_out[r * NHEADS + col - 4] = acc[8][i];
        }
    }
}

// ---------------- CSR build: counting sort of edges by dst ----------------
__global__ void k_zero(int* __restrict__ p, int n) {
    int i = blockIdx.x * 256 + threadIdx.x;
    if (i < n) p[i] = 0;
}

__global__ void k_hist(const int* __restrict__ dst, int* __restrict__ deg, int E, int N) {
    int i = blockIdx.x * 256 + threadIdx.x;
    if (i >= E + N) return;
    int d = (i < E) ? dst[i] : (i - E);
    atomicAdd(&deg[d], 1);
}

__global__ void k_scan1(const int* __restrict__ deg, int* __restrict__ tmp,
                        int* __restrict__ bsum, int N) {
    __shared__ int sh[256];
    int t = threadIdx.x, i = blockIdx.x * 256 + t;
    sh[t] = (i < N) ? deg[i] : 0;
    __syncthreads();
    for (int off = 1; off < 256; off <<= 1) {
        int u = (t >= off) ? sh[t - off] : 0;
        __syncthreads();
        sh[t] += u;
        __syncthreads();
    }
    if (i < N) tmp[i] = sh[t];
    if (t == 255) bsum[blockIdx.x] = sh[255];
}

__global__ void k_scan2(const int* __restrict__ bsum, int* __restrict__ ebsum, int nblk) {
    __shared__ int sh[512];
    int t = threadIdx.x;
    int v = (t < nblk) ? bsum[t] : 0;
    sh[t] = v;
    __syncthreads();
    for (int off = 1; off < 512; off <<= 1) {
        int u = (t >= off) ? sh[t - off] : 0;
        __syncthreads();
        sh[t] += u;
        __syncthreads();
    }
    if (t < nblk) ebsum[t] = sh[t] - v;
}

__global__ void k_scan3(const int* __restrict__ tmp, const int* __restrict__ ebsum,
                        const int* __restrict__ deg, int* __restrict__ rowptr,
                        int* __restrict__ cursor, int N) {
    int i = blockIdx.x * 256 + threadIdx.x;
    if (i >= N) return;
    int incl = tmp[i] + ebsum[i >> 8];
    int excl = incl - deg[i];
    rowptr[i] = excl;
    cursor[i] = excl;
    if (i == N - 1) rowptr[N] = incl;
}

__global__ void k_scatter(const int* __restrict__ src, const int* __restrict__ dst,
                          int* __restrict__ cursor, int* __restrict__ ssrc, int E, int N) {
    int i = blockIdx.x * 256 + threadIdx.x;
    if (i >= E + N) return;
    int s, d;
    if (i < E) { s = src[i]; d = dst[i]; } else { s = d = i - E; }
    int pos = atomicAdd(&cursor[d], 1);
    ssrc[pos] = s;
}

// ------------- degree sort: block-local counting sort (no global atomics) ------
__global__ __launch_bounds__(256) void k_sort_hist(
    const int* __restrict__ deg, int* __restrict__ bh, int N)
{
    __shared__ int hist[256];
    int t = threadIdx.x;
    hist[t] = 0;
    __syncthreads();
    int base = blockIdx.x * 1024;
    #pragma unroll
    for (int g = 0; g < 4; ++g) {
        int i = base + g * 256 + t;
        if (i < N) atomicAdd(&hist[min(deg[i], 255)], 1);
    }
    __syncthreads();
    bh[blockIdx.x * 256 + t] = hist[t];
}

__global__ __launch_bounds__(256) void k_sort_off(int* __restrict__ bh, int nb)
{
    int t = threadIdx.x;
    int run = 0;
    for (int j = 0; j < nb; ++j) {
        int v = bh[j * 256 + t];
        bh[j * 256 + t] = run;
        run += v;
    }
    __shared__ int sh[256];
    int tot = run;
    sh[t] = tot;
    __syncthreads();
    for (int off = 1; off < 256; off <<= 1) {
        int u = (t >= off) ? sh[t - off] : 0;
        __syncthreads();
        sh[t] += u;
        __syncthreads();
    }
    int bucket_base = sh[t] - tot;   // exclusive
    for (int j = 0; j < nb; ++j)
        bh[j * 256 + t] += bucket_base;
}

__global__ __launch_bounds__(256) void k_sort_scatter(
    const int* __restrict__ deg, const int* __restrict__ bh,
    int* __restrict__ order, int N)
{
    __shared__ int cur[256];
    int t = threadIdx.x;
    cur[t] = bh[blockIdx.x * 256 + t];
    __syncthreads();
    int base = blockIdx.x * 1024;
    #pragma unroll
    for (int g = 0; g < 4; ++g) {
        int i = base + g * 256 + t;
        if (i < N) {
            int pos = atomicAdd(&cur[min(deg[i], 255)], 1);
            order[pos] = i;
        }
    }
}

// ---------------- single-pass softmax + weighted aggregation ----------------
// 16 lanes per node (degree-sorted order), 4 nodes per wave. Each lane owns 8
// channels of one head; per-head denominator is lane-local (no reductions).
// 8 edges batched per iteration: all 8 ssrc, 8 as, 8 h-row gathers issued
// back-to-back for memory-level parallelism; tail edges are index-clamped
// (duplicate gathers hit cache) and predicated out of the math.
template<bool OUTBF16>
__global__ __launch_bounds__(256) void k_aggregate(
    const int* __restrict__ rowptr, const int* __restrict__ ssrc,
    const int* __restrict__ order,
    const float* __restrict__ as, const float* __restrict__ ad,
    const unsigned short* __restrict__ hbf, const float* __restrict__ bias,
    void* __restrict__ outv, int N)
{
    int gi = (blockIdx.x * 256 + threadIdx.x) >> 4;   // global 16-lane group id
    if (gi >= N) return;
    const int node  = order[gi];
    const int l16   = threadIdx.x & 15;
    const int hb    = l16 >> 2;                       // head owning my channels
    const int c0    = l16 * 8;                        // first of my 8 channels
    const int start = rowptr[node], end = rowptr[node + 1];
    const float adB = ad[node * NHEADS + hb];

    float a0=0.f,a1=0.f,a2=0.f,a3=0.f,a4=0.f,a5=0.f,a6=0.f,a7=0.f;
    float dacc = 0.f;
    for (int base = start; base < end; base += 8) {
        int   sj[8];
        float fj[8];
        uint4 hj[8];
        #pragma unroll
        for (int j = 0; j < 8; ++j)
            sj[j] = ssrc[min(base + j, end - 1)];
        #pragma unroll
        for (int j = 0; j < 8; ++j)
            fj[j] = as[sj[j] * NHEADS + hb];
        #pragma unroll
        for (int j = 0; j < 8; ++j)
            hj[j] = *(const uint4*)(hbf + (size_t)sj[j] * F + c0);
        #pragma unroll
        for (int j = 0; j < 8; ++j) {
            float ex = (base + j < end) ? __expf(lrelu(fj[j] + adB)) : 0.f;
            dacc += ex;
            a0 = fmaf(ex, __uint_as_float(hj[j].x << 16),         a0);
            a1 = fmaf(ex, __uint_as_float(hj[j].x & 0xffff0000u), a1);
            a2 = fmaf(ex, __uint_as_float(hj[j].y << 16),         a2);
            a3 = fmaf(ex, __uint_as_float(hj[j].y & 0xffff0000u), a3);
            a4 = fmaf(ex, __uint_as_float(hj[j].z << 16),         a4);
            a5 = fmaf(ex, __uint_as_float(hj[j].z & 0xffff0000u), a5);
            a6 = fmaf(ex, __uint_as_float(hj[j].w << 16),         a6);
            a7 = fmaf(ex, __uint_as_float(hj[j].w & 0xffff0000u), a7);
        }
    }
    float inv = 1.f / dacc;                // deg >= 1 (self-loop), all exp > 0
    float v[8] = {a0,a1,a2,a3,a4,a5,a6,a7};
    #pragma unroll
    for (int k = 0; k < 8; ++k) {
        float t = v[k] * inv + bias[c0 + k];
        v[k] = t > 0.f ? t : expm1f(t);
    }
    if (OUTBF16) {
        unsigned r0 = (unsigned)cvt_bf16(v[0]) | ((unsigned)cvt_bf16(v[1]) << 16);
        unsigned r1 = (unsigned)cvt_bf16(v[2]) | ((unsigned)cvt_bf16(v[3]) << 16);
        unsigned r2 = (unsigned)cvt_bf16(v[4]) | ((unsigned)cvt_bf16(v[5]) << 16);
        unsigned r3 = (unsigned)cvt_bf16(v[6]) | ((unsigned)cvt_bf16(v[7]) << 16);
        uint4 o = {r0, r1, r2, r3};
        *(uint4*)((unsigned short*)outv + (size_t)node * F + c0) = o;
    } else {
        float4 o0 = {v[0], v[1], v[2], v[3]};
        float4 o1 = {v[4], v[5], v[6], v[7]};
        float* op = (float*)outv + (size_t)node * F + c0;
        *(float4*)op       = o0;
        *(float4*)(op + 4) = o1;
    }
}

extern "C" void kernel_launch(void* const* d_in, const int* in_sizes, int n_in,
                              void* d_out, int out_size, void* d_ws, size_t ws_size,
                              hipStream_t stream)
{
    const float* x      = (const float*)d_in[0];
    const int*   eidx   = (const int*)d_in[1];
    const float* W1     = (const float*)d_in[2];
    const float* a_src1 = (const float*)d_in[3];
    const float* a_dst1 = (const float*)d_in[4];
    const float* b1     = (const float*)d_in[5];
    const float* W2     = (const float*)d_in[6];
    const float* a_src2 = (const float*)d_in[7];
    const float* a_dst2 = (const float*)d_in[8];
    const float* b2     = (const float*)d_in[9];

    const int N = in_sizes[0] / F;
    const int E = in_sizes[1] / 2;
    const int TOT = E + N;
    const int* src = eidx;
    const int* dst = eidx + E;

    // workspace layout
    unsigned short* hbf    = (unsigned short*)d_ws;        // N*F bf16
    unsigned short* out1bf = hbf + (size_t)N * F;          // N*F bf16
    float* as = (float*)(out1bf + (size_t)N * F);          // N*4
    float* ad = as + (size_t)N * NHEADS;                   // N*4
    int* deg    = (int*)(ad + (size_t)N * NHEADS);
    int* rowptr = deg + N;                                 // N+1
    int* cursor = rowptr + N + 1;                          // N
    int* bsum   = cursor + N;                              // <=512
    int* ebsum  = bsum + 512;                              // <=512
    int* tmp    = ebsum + 512;                             // N
    int* ssrc   = tmp + N;                                 // TOT
    int* order  = ssrc + TOT;                              // N
    const int nb = (N + 1023) / 1024;                      // sort blocks
    int* bh     = order + N;                               // nb*256
    short* Wb1  = (short*)(((uintptr_t)(bh + (size_t)nb * 256) + 15) & ~(uintptr_t)15);
    short* Wb2  = Wb1 + 36 * 512;

    const int nblk = (N + 255) / 256;
    const int gemmBlocks = (N + 63) / 64;
    const int aggBlocks  = (N + 15) / 16;     // 16 nodes per 256-thread block

    // ---- W pre-pack + CSR build + degree sort (reused by both layers) ----
    k_packW<<<72, 256, 0, stream>>>(W1, a_src1, a_dst1, Wb1);
    k_packW<<<72, 256, 0, stream>>>(W2, a_src2, a_dst2, Wb2);
    k_zero<<<nblk, 256, 0, stream>>>(deg, N);
    k_hist<<<(TOT + 255) / 256, 256, 0, stream>>>(dst, deg, E, N);
    k_scan1<<<nblk, 256, 0, stream>>>(deg, tmp, bsum, N);
    k_scan2<<<1, 512, 0, stream>>>(bsum, ebsum, nblk);
    k_scan3<<<nblk, 256, 0, stream>>>(tmp, ebsum, deg, rowptr, cursor, N);
    k_scatter<<<(TOT + 255) / 256, 256, 0, stream>>>(src, dst, cursor, ssrc, E, N);
    k_sort_hist<<<nb, 256, 0, stream>>>(deg, bh, N);
    k_sort_off<<<1, 256, 0, stream>>>(bh, nb);
    k_sort_scatter<<<nb, 256, 0, stream>>>(deg, bh, order, N);

    // ---- layer 1: x (f32) -> out1bf (bf16) ----
    k_gemm_mfma<false><<<gemmBlocks, 256, 0, stream>>>(x, Wb1, hbf, as, ad, N);
    k_aggregate<true><<<aggBlocks, 256, 0, stream>>>(rowptr, ssrc, order, as, ad, hbf, b1, out1bf, N);

    // ---- layer 2: out1bf (bf16) -> d_out (f32) ----
    k_gemm_mfma<true><<<gemmBlocks, 256, 0, stream>>>(out1bf, Wb2, hbf, as, ad, N);
    k_aggregate<false><<<aggBlocks, 256, 0, stream>>>(rowptr, ssrc, order, as, ad, hbf, b2, d_out, N);
}